// Round 7
// baseline (284.832 us; speedup 1.0000x reference)
//
#include <hip/hip_runtime.h>
#include <hip/hip_cooperative_groups.h>
#include <hip/hip_fp16.h>
#include <cstdint>
#include <cstddef>

namespace cg = cooperative_groups;

// Problem constants
#define B_ 16
#define K_ 49
#define T_ 256
#define H_ 512
#define D_ 512

// tanh(x) = 1 - 2*rcp(1 + 2^(x*2*log2e)); TANH_SCALE folded into Wv/Wg/Ws(+biases),
// gemm epilogue stores 2^(scaled dot) so the z phase inner loop is pure fma/rcp.
#define TANH_SCALE 2.8853900817779268f
#define LOG2E 1.4426950408889634f

typedef _Float16 half8 __attribute__((ext_vector_type(8)));
typedef float floatx4 __attribute__((ext_vector_type(4)));

// A matrix (fp16) rows: [0,784)=V, [784,896)=pad0, [896,4992)=h_t, [4992,9088)=s_t
#define OFF_V 0
#define OFF_H 896
#define OFF_S 4992

__device__ __forceinline__ void async16(const _Float16* g, const _Float16* l) {
    __builtin_amdgcn_global_load_lds(
        (const __attribute__((address_space(1))) unsigned int*)g,
        (__attribute__((address_space(3))) unsigned int*)l, 16, 0, 0);
}

__device__ __forceinline__ float wave_sum(float v) {
#pragma unroll
    for (int o = 32; o > 0; o >>= 1) v += __shfl_xor(v, o);
    return v;
}
__device__ __forceinline__ float wave_max(float v) {
#pragma unroll
    for (int o = 32; o > 0; o >>= 1) v = fmaxf(v, __shfl_xor(v, o));
    return v;
}
// Sum 4 independent values across 64 lanes (group g=lane>>4 holds acc_g's total).
__device__ __forceinline__ float xsum4(float a0, float a1, float a2, float a3, int lane) {
    bool hi = (lane & 32) != 0;
    float t0 = hi ? a0 : a2;
    float t1 = hi ? a1 : a3;
    t0 = __shfl_xor(t0, 32);
    t1 = __shfl_xor(t1, 32);
    if (hi) { a0 = t0; a1 = t1; } else { a2 = t0; a3 = t1; }
    bool h2 = (lane & 16) != 0;
    float u0 = h2 ? a0 : a1;
    float u1 = h2 ? a2 : a3;
    u0 = __shfl_xor(u0, 16);
    u1 = __shfl_xor(u1, 16);
    if (h2) { a0 = u0; a2 = u1; } else { a1 = u0; a3 = u1; }
    float s = (a0 + a1) + (a2 + a3);
#pragma unroll
    for (int o = 8; o > 0; o >>= 1) s += __shfl_xor(s, o);
    return s;
}

#define TB 4

// ====================== fused cooperative kernel (grid-size agnostic) ======================
__global__ __launch_bounds__(256, 4) void fused_all(
    const float* __restrict__ V, const float* __restrict__ h_t,
    const float* __restrict__ s_t, const float* __restrict__ Wv,
    const float* __restrict__ Wg, const float* __restrict__ Ws,
    const float* __restrict__ bv, const float* __restrict__ bg2,
    const float* __restrict__ bs, const float* __restrict__ Wh,
    const float* __restrict__ bh, _Float16* __restrict__ Af16,
    _Float16* __restrict__ Wt, float* __restrict__ ecv,
    float* __restrict__ ecg, float* __restrict__ ecs,
    float* __restrict__ out)
{
    extern __shared__ __align__(16) char smem[];   // 16384 B dynamic
    cg::grid_group grid = cg::this_grid();
    int blk = blockIdx.x;
    int nblk = gridDim.x;
    int tid = threadIdx.x;
    int wave = tid >> 6, lane = tid & 63;

    // ================= Phase A: conversions =================
    for (int c = blk * 256 + tid; c < 581632; c += nblk * 256) {
        int idx = c * 8;
        int row = idx >> 9;
        int col = idx & 511;
        const float* src;
        if (row < 784)        src = V   + (size_t)row * 512 + col;
        else if (row < 896)   src = nullptr;                       // pad -> 0
        else if (row < 4992)  src = h_t + (size_t)(row - 896) * 512 + col;
        else                  src = s_t + (size_t)(row - 4992) * 512 + col;
        half8 h;
        if (src) {
            float4 f0 = *(const float4*)(src);
            float4 f1 = *(const float4*)(src + 4);
            h[0] = (_Float16)f0.x; h[1] = (_Float16)f0.y;
            h[2] = (_Float16)f0.z; h[3] = (_Float16)f0.w;
            h[4] = (_Float16)f1.x; h[5] = (_Float16)f1.y;
            h[6] = (_Float16)f1.z; h[7] = (_Float16)f1.w;
        } else {
            h = (half8)((_Float16)0.0f);
        }
        *(half8*)(Af16 + idx) = h;
    }
    // W-conv + transpose (+TANH_SCALE): 768 32x32 tiles, grid-strided
    for (int wt = blk; wt < 768; wt += nblk) {
        __syncthreads();                          // LDS reuse guard
        float* tile = (float*)smem;               // [32][33]
        int p = wt >> 8;
        int rem = wt & 255;
        int bx = rem & 15, by = rem >> 4;
        const float* W = (p == 0) ? Wv : (p == 1) ? Wg : Ws;
        _Float16* outp = Wt + (size_t)p * 512 * 512;
        int tx = tid & 31, ty = tid >> 5;
        int c = bx * 32 + tx;
        int rbase = by * 32;
#pragma unroll
        for (int i = 0; i < 4; i++)
            tile[(ty + i * 8) * 33 + tx] = W[(size_t)(rbase + ty + i * 8) * 512 + c];
        __syncthreads();
        int k = rbase + tx;
#pragma unroll
        for (int i = 0; i < 4; i++) {
            int n = bx * 32 + ty + i * 8;
            outp[(size_t)n * 512 + k] = (_Float16)(tile[tx * 33 + ty + i * 8] * TANH_SCALE);
        }
    }
    grid.sync();

    // ================= Phase B: 3-problem fp16 MFMA GEMM, 64x64 tiles =================
    {
        _Float16* As = (_Float16*)smem;           // 8 KB
        _Float16* Bs = As + 4096;                 // 8 KB
        for (int tile_id = blk; tile_id < 1136; tile_id += nblk) {
            __syncthreads();                      // LDS reuse guard

            int id = tile_id;
            int rowbase; const _Float16* Bt; const float* bias; float* C;
            if (id < 112)       { rowbase = OFF_V;            Bt = Wt;          bias = bv;  C = ecv; }
            else if (id < 624)  { id -= 112; rowbase = OFF_H; Bt = Wt + 262144; bias = bg2; C = ecg; }
            else                { id -= 624; rowbase = OFF_S; Bt = Wt + 524288; bias = bs;  C = ecs; }
            int tm = id >> 3, tn = id & 7;

            // chunk p (0..511): ks=p>>8, x=(p>>6)&3, q=(p>>4)&3, f=p&15 ; LDS addr p*8
            const _Float16* gA[2]; const _Float16* gB[2]; int ldsA[2];
#pragma unroll
            for (int i = 0; i < 2; i++) {
                int p = i * 256 + tid;
                int ks = p >> 8, x = (p >> 6) & 3, q = (p >> 4) & 3, f = p & 15;
                gA[i] = Af16 + (size_t)(rowbase + tm * 64 + x * 16 + f) * 512 + ks * 32 + q * 8;
                gB[i] = Bt   + (size_t)(tn * 64 + x * 16 + f) * 512 + ks * 32 + q * 8;
                ldsA[i] = p * 8;
            }

            floatx4 acc[4];
#pragma unroll
            for (int x = 0; x < 4; x++) acc[x] = (floatx4)0.0f;

            for (int kk = 0; kk < 8; kk++) {
                if (kk) __syncthreads();
#pragma unroll
                for (int i = 0; i < 2; i++) async16(gA[i] + kk * 64, As + ldsA[i]);
#pragma unroll
                for (int i = 0; i < 2; i++) async16(gB[i] + kk * 64, Bs + ldsA[i]);
                __syncthreads();                  // drains vmcnt(0): LDS visible

#pragma unroll
                for (int ks = 0; ks < 2; ks++) {
                    half8 a[4];
#pragma unroll
                    for (int x = 0; x < 4; x++)
                        a[x] = *(const half8*)&As[(ks * 256 + x * 64 + lane) * 8];
                    half8 b = *(const half8*)&Bs[(ks * 256 + wave * 64 + lane) * 8];
#pragma unroll
                    for (int x = 0; x < 4; x++)
                        acc[x] = __builtin_amdgcn_mfma_f32_16x16x32_f16(a[x], b, acc[x], 0, 0, 0);
                }
            }

            int dn = lane & 15, dq = lane >> 4;
            int colg = tn * 64 + wave * 16 + dn;
            float bc = bias[colg] * TANH_SCALE;
#pragma unroll
            for (int x = 0; x < 4; x++) {
                int rowg = tm * 64 + x * 16 + dq * 4;
#pragma unroll
                for (int r = 0; r < 4; r++)
                    C[(size_t)(rowg + r) * 512 + colg] = __builtin_amdgcn_exp2f(acc[x][r] + bc);
            }
        }
    }
    grid.sync();

    // ================= Phase C: z / softmax / c_t / gate =================
    for (int task = blk; task < 1024; task += nblk) {
        __syncthreads();                          // LDS reuse guard
        float*  zl  = (float*)smem;               // [TB][64]
        float4* al4 = (float4*)(smem + 1024);     // 52 float4
        float*  bl  = (float*)(smem + 1856);      // TB floats

        int b  = task >> 6;
        int t0 = (task & 63) << 2;
        int bt0 = b * 256 + t0;

        float whv[8], egv[TB][8];
#pragma unroll
        for (int j = 0; j < 8; j++) whv[j] = Wh[j * 64 + lane];
#pragma unroll
        for (int tt = 0; tt < TB; tt++) {
            const float* cgp = ecg + (size_t)(bt0 + tt) * 512;
#pragma unroll
            for (int j = 0; j < 8; j++) egv[tt][j] = cgp[j * 64 + lane];
        }
        float s8 = 0.0f;
#pragma unroll
        for (int j = 0; j < 8; j++) s8 += whv[j];
        float zbase = wave_sum(s8) + bh[0];       // sum(Wh)+bh: tanh = 1-2r folded

        float rv[8], rn[8];
        {
            const float* rp = ecv + (size_t)(b * 49 + wave) * 512;
#pragma unroll
            for (int j = 0; j < 8; j++) rv[j] = rp[j * 64 + lane];
        }
        for (int tk = wave; tk < 49; tk += 4) {
            int nt = tk + 4;
            if (nt < 49) {
                const float* rp = ecv + (size_t)(b * 49 + nt) * 512;
#pragma unroll
                for (int j = 0; j < 8; j++) rn[j] = rp[j * 64 + lane];
            }
            float acc[TB] = {0.0f, 0.0f, 0.0f, 0.0f};
#pragma unroll
            for (int tt = 0; tt < TB; tt++) {
#pragma unroll
                for (int j = 0; j < 8; j++) {
                    float t = fmaf(rv[j], egv[tt][j], 1.0f);   // 1 + 2^(cv+cg)
                    float r = __builtin_amdgcn_rcpf(t);
                    acc[tt] = fmaf(whv[j], r, acc[tt]);
                }
            }
            float z = xsum4(acc[0], acc[1], acc[2], acc[3], lane);
            if ((lane & 15) == 0) zl[(lane >> 4) * 64 + tk] = zbase - 2.0f * z;
#pragma unroll
            for (int j = 0; j < 8; j++) rv[j] = rn[j];
        }
#pragma unroll
        for (int tt = 0; tt < TB; tt++) {
            if (wave == tt) {
                const float* rp = ecs + (size_t)(bt0 + tt) * 512;
                float acc = 0.0f;
#pragma unroll
                for (int j = 0; j < 8; j++) {
                    float t = fmaf(rp[j * 64 + lane], egv[tt][j], 1.0f);
                    float r = __builtin_amdgcn_rcpf(t);
                    acc = fmaf(whv[j], r, acc);
                }
                float s = wave_sum(acc);
                if (lane == 0) zl[tt * 64 + 49] = zbase - 2.0f * s;
            }
        }
        __syncthreads();

        {
            int w = wave;
            float z = (lane < 49) ? zl[w * 64 + lane] : -3.0e38f;
            float m = wave_max(z);
            float e = (lane < 49) ? __builtin_amdgcn_exp2f((z - m) * LOG2E) : 0.0f;
            float s = wave_sum(e);
            float zext = zl[w * 64 + 49];
            float m2 = fmaxf(m, zext);
            float sc   = __builtin_amdgcn_exp2f((m - m2) * LOG2E);
            float eext = __builtin_amdgcn_exp2f((zext - m2) * LOG2E);
            float s2 = s * sc + eext;
            float beta = eext / s2;
            if (lane < 49) {
                float a = e / s;
                ((float*)(al4 + lane))[w] = a;
                out[(size_t)B_ * T_ * H_ + (size_t)(bt0 + w) * 49 + lane] = a;   // alpha_t
            }
            if (lane == 0) {
                bl[w] = beta;
                out[(size_t)B_ * T_ * H_ + (size_t)B_ * T_ * K_ + (bt0 + w)] = beta;  // beta_t
            }
        }
        __syncthreads();

        const float* Vb = V + (size_t)b * 49 * 512;
        float2 accA[TB];
#pragma unroll
        for (int tt = 0; tt < TB; tt++) accA[tt] = make_float2(0.0f, 0.0f);
#pragma unroll 7
        for (int k = 0; k < 49; k++) {
            float4 a4 = al4[k];
            float2 v = *(const float2*)(Vb + (size_t)k * 512 + tid * 2);
            accA[0].x = fmaf(a4.x, v.x, accA[0].x);  accA[0].y = fmaf(a4.x, v.y, accA[0].y);
            accA[1].x = fmaf(a4.y, v.x, accA[1].x);  accA[1].y = fmaf(a4.y, v.y, accA[1].y);
            accA[2].x = fmaf(a4.z, v.x, accA[2].x);  accA[2].y = fmaf(a4.z, v.y, accA[2].y);
            accA[3].x = fmaf(a4.w, v.x, accA[3].x);  accA[3].y = fmaf(a4.w, v.y, accA[3].y);
        }
#pragma unroll
        for (int tt = 0; tt < TB; tt++) {
            float beta = bl[tt];
            float2 sp = *(const float2*)(s_t + (size_t)(bt0 + tt) * 512 + tid * 2);
            float2 o;
            o.x = beta * sp.x + (1.0f - beta) * accA[tt].x;
            o.y = beta * sp.y + (1.0f - beta) * accA[tt].y;
            *(float2*)(out + (size_t)(bt0 + tt) * 512 + tid * 2) = o;
        }
    }
}

// ====================== R5 fallback kernels (known-good) ======================
__global__ __launch_bounds__(256) void conv_all(const float* __restrict__ V,
                                                const float* __restrict__ h_t,
                                                const float* __restrict__ s_t,
                                                const float* __restrict__ Wv,
                                                const float* __restrict__ Wg,
                                                const float* __restrict__ Ws,
                                                _Float16* __restrict__ Af16,
                                                _Float16* __restrict__ Wt) {
    __shared__ float tile[32][33];
    int tid = threadIdx.x;
    if (blockIdx.x < 2272) {
        int idx = (blockIdx.x * 256 + tid) * 8;
        int row = idx >> 9;
        int col = idx & 511;
        const float* src;
        if (row < 784)        src = V   + (size_t)row * 512 + col;
        else if (row < 896)   src = nullptr;
        else if (row < 4992)  src = h_t + (size_t)(row - 896) * 512 + col;
        else                  src = s_t + (size_t)(row - 4992) * 512 + col;
        half8 h;
        if (src) {
            float4 f0 = *(const float4*)(src);
            float4 f1 = *(const float4*)(src + 4);
            h[0] = (_Float16)f0.x; h[1] = (_Float16)f0.y;
            h[2] = (_Float16)f0.z; h[3] = (_Float16)f0.w;
            h[4] = (_Float16)f1.x; h[5] = (_Float16)f1.y;
            h[6] = (_Float16)f1.z; h[7] = (_Float16)f1.w;
        } else {
            h = (half8)((_Float16)0.0f);
        }
        *(half8*)(Af16 + idx) = h;
    } else {
        int bid = blockIdx.x - 2272;
        int p = bid >> 8;
        int rem = bid & 255;
        int bx = rem & 15, by = rem >> 4;
        const float* W = (p == 0) ? Wv : (p == 1) ? Wg : Ws;
        _Float16* outp = Wt + (size_t)p * 512 * 512;
        int tx = tid & 31, ty = tid >> 5;
        int c = bx * 32 + tx;
        int rbase = by * 32;
#pragma unroll
        for (int i = 0; i < 4; i++)
            tile[ty + i * 8][tx] = W[(size_t)(rbase + ty + i * 8) * 512 + c];
        __syncthreads();
        int k = rbase + tx;
#pragma unroll
        for (int i = 0; i < 4; i++) {
            int n = bx * 32 + ty + i * 8;
            outp[(size_t)n * 512 + k] = (_Float16)(tile[tx][ty + i * 8] * TANH_SCALE);
        }
    }
}

__global__ __launch_bounds__(256) void gemm_f16(
    const _Float16* __restrict__ Af16, const _Float16* __restrict__ Wt,
    const float* __restrict__ bv, const float* __restrict__ bg2,
    const float* __restrict__ bs, float* __restrict__ cv,
    float* __restrict__ cg2, float* __restrict__ cs) {
    __shared__ __align__(16) _Float16 As[64 * 64];
    __shared__ __align__(16) _Float16 Bs[64 * 64];

    int id = blockIdx.x;
    int rowbase; const _Float16* Bt; const float* bias; float* C;
    if (id < 112)       { rowbase = OFF_V;            Bt = Wt;          bias = bv;  C = cv; }
    else if (id < 624)  { id -= 112; rowbase = OFF_H; Bt = Wt + 262144; bias = bg2; C = cg2; }
    else                { id -= 624; rowbase = OFF_S; Bt = Wt + 524288; bias = bs;  C = cs; }
    int tm = id >> 3, tn = id & 7;

    int tid = threadIdx.x;
    int wave = tid >> 6, lane = tid & 63;

    const _Float16* gA[2]; const _Float16* gB[2]; int ldsA[2];
#pragma unroll
    for (int i = 0; i < 2; i++) {
        int p = i * 256 + tid;
        int ks = p >> 8, x = (p >> 6) & 3, q = (p >> 4) & 3, f = p & 15;
        gA[i] = Af16 + (size_t)(rowbase + tm * 64 + x * 16 + f) * 512 + ks * 32 + q * 8;
        gB[i] = Bt   + (size_t)(tn * 64 + x * 16 + f) * 512 + ks * 32 + q * 8;
        ldsA[i] = p * 8;
    }

    floatx4 acc[4];
#pragma unroll
    for (int x = 0; x < 4; x++) acc[x] = (floatx4)0.0f;

    for (int kk = 0; kk < 8; kk++) {
        if (kk) __syncthreads();
#pragma unroll
        for (int i = 0; i < 2; i++) async16(gA[i] + kk * 64, As + ldsA[i]);
#pragma unroll
        for (int i = 0; i < 2; i++) async16(gB[i] + kk * 64, Bs + ldsA[i]);
        __syncthreads();

#pragma unroll
        for (int ks = 0; ks < 2; ks++) {
            half8 a[4];
#pragma unroll
            for (int x = 0; x < 4; x++)
                a[x] = *(const half8*)&As[(ks * 256 + x * 64 + lane) * 8];
            half8 b = *(const half8*)&Bs[(ks * 256 + wave * 64 + lane) * 8];
#pragma unroll
            for (int x = 0; x < 4; x++)
                acc[x] = __builtin_amdgcn_mfma_f32_16x16x32_f16(a[x], b, acc[x], 0, 0, 0);
        }
    }

    int dn = lane & 15, dq = lane >> 4;
    int colg = tn * 64 + wave * 16 + dn;
    float bc = bias[colg] * TANH_SCALE;
#pragma unroll
    for (int x = 0; x < 4; x++) {
        int rowg = tm * 64 + x * 16 + dq * 4;
#pragma unroll
        for (int r = 0; r < 4; r++)
            C[(size_t)(rowg + r) * 512 + colg] = __builtin_amdgcn_exp2f(acc[x][r] + bc);
    }
}

__global__ __launch_bounds__(256) void z_kernel(
    const float* __restrict__ ecv, const float* __restrict__ ecg,
    const float* __restrict__ ecs, const float* __restrict__ V,
    const float* __restrict__ s_t, const float* __restrict__ Wh,
    const float* __restrict__ bh, float* __restrict__ out) {
    int bx = blockIdx.x;
    int b  = bx >> 6;
    int t0 = (bx & 63) << 2;
    int bt0 = b * 256 + t0;
    int tid = threadIdx.x;
    int wave = tid >> 6, lane = tid & 63;

    __shared__ float zl[TB][64];
    __shared__ float4 al4[52];
    __shared__ float bl[TB];

    float whv[8], egv[TB][8];
#pragma unroll
    for (int j = 0; j < 8; j++) whv[j] = Wh[j * 64 + lane];
#pragma unroll
    for (int tt = 0; tt < TB; tt++) {
        const float* cgp = ecg + (size_t)(bt0 + tt) * 512;
#pragma unroll
        for (int j = 0; j < 8; j++) egv[tt][j] = cgp[j * 64 + lane];
    }
    float s8 = 0.0f;
#pragma unroll
    for (int j = 0; j < 8; j++) s8 += whv[j];
    float zbase = wave_sum(s8) + bh[0];

    float rv[8], rn[8];
    {
        const float* rp = ecv + (size_t)(b * 49 + wave) * 512;
#pragma unroll
        for (int j = 0; j < 8; j++) rv[j] = rp[j * 64 + lane];
    }
    for (int task = wave; task < 49; task += 4) {
        int nt = task + 4;
        if (nt < 49) {
            const float* rp = ecv + (size_t)(b * 49 + nt) * 512;
#pragma unroll
            for (int j = 0; j < 8; j++) rn[j] = rp[j * 64 + lane];
        }
        float acc[TB] = {0.0f, 0.0f, 0.0f, 0.0f};
#pragma unroll
        for (int tt = 0; tt < TB; tt++) {
#pragma unroll
            for (int j = 0; j < 8; j++) {
                float t = fmaf(rv[j], egv[tt][j], 1.0f);
                float r = __builtin_amdgcn_rcpf(t);
                acc[tt] = fmaf(whv[j], r, acc[tt]);
            }
        }
        float z = xsum4(acc[0], acc[1], acc[2], acc[3], lane);
        if ((lane & 15) == 0) zl[lane >> 4][task] = zbase - 2.0f * z;
#pragma unroll
        for (int j = 0; j < 8; j++) rv[j] = rn[j];
    }
#pragma unroll
    for (int tt = 0; tt < TB; tt++) {
        if (wave == tt) {
            const float* rp = ecs + (size_t)(bt0 + tt) * 512;
            float acc = 0.0f;
#pragma unroll
            for (int j = 0; j < 8; j++) {
                float t = fmaf(rp[j * 64 + lane], egv[tt][j], 1.0f);
                float r = __builtin_amdgcn_rcpf(t);
                acc = fmaf(whv[j], r, acc);
            }
            float s = wave_sum(acc);
            if (lane == 0) zl[tt][49] = zbase - 2.0f * s;
        }
    }
    __syncthreads();

    {
        int w = wave;
        float z = (lane < 49) ? zl[w][lane] : -3.0e38f;
        float m = wave_max(z);
        float e = (lane < 49) ? __builtin_amdgcn_exp2f((z - m) * LOG2E) : 0.0f;
        float s = wave_sum(e);
        float zext = zl[w][49];
        float m2 = fmaxf(m, zext);
        float sc   = __builtin_amdgcn_exp2f((m - m2) * LOG2E);
        float eext = __builtin_amdgcn_exp2f((zext - m2) * LOG2E);
        float s2 = s * sc + eext;
        float beta = eext / s2;
        if (lane < 49) {
            float a = e / s;
            ((float*)&al4[lane])[w] = a;
            out[(size_t)B_ * T_ * H_ + (size_t)(bt0 + w) * 49 + lane] = a;
        }
        if (lane == 0) {
            bl[w] = beta;
            out[(size_t)B_ * T_ * H_ + (size_t)B_ * T_ * K_ + (bt0 + w)] = beta;
        }
    }
    __syncthreads();

    const float* Vb = V + (size_t)b * 49 * 512;
    float2 accA[TB];
#pragma unroll
    for (int tt = 0; tt < TB; tt++) accA[tt] = make_float2(0.0f, 0.0f);
#pragma unroll 7
    for (int k = 0; k < 49; k++) {
        float4 a4 = al4[k];
        float2 v = *(const float2*)(Vb + (size_t)k * 512 + tid * 2);
        accA[0].x = fmaf(a4.x, v.x, accA[0].x);  accA[0].y = fmaf(a4.x, v.y, accA[0].y);
        accA[1].x = fmaf(a4.y, v.x, accA[1].x);  accA[1].y = fmaf(a4.y, v.y, accA[1].y);
        accA[2].x = fmaf(a4.z, v.x, accA[2].x);  accA[2].y = fmaf(a4.z, v.y, accA[2].y);
        accA[3].x = fmaf(a4.w, v.x, accA[3].x);  accA[3].y = fmaf(a4.w, v.y, accA[3].y);
    }
#pragma unroll
    for (int tt = 0; tt < TB; tt++) {
        float beta = bl[tt];
        float2 sp = *(const float2*)(s_t + (size_t)(bt0 + tt) * 512 + tid * 2);
        float2 o;
        o.x = beta * sp.x + (1.0f - beta) * accA[tt].x;
        o.y = beta * sp.y + (1.0f - beta) * accA[tt].y;
        *(float2*)(out + (size_t)(bt0 + tt) * 512 + tid * 2) = o;
    }
}

// ---------------- launch ----------------
extern "C" void kernel_launch(void* const* d_in, const int* in_sizes, int n_in,
                              void* d_out, int out_size, void* d_ws, size_t ws_size,
                              hipStream_t stream) {
    const float* V   = (const float*)d_in[0];
    const float* h_t = (const float*)d_in[1];
    const float* s_t = (const float*)d_in[2];
    const float* Wv  = (const float*)d_in[3];
    const float* bv  = (const float*)d_in[4];
    const float* Wg  = (const float*)d_in[5];
    const float* bg  = (const float*)d_in[6];
    const float* Ws  = (const float*)d_in[7];
    const float* bs  = (const float*)d_in[8];
    const float* Wh  = (const float*)d_in[9];
    const float* bh  = (const float*)d_in[10];
    float* out = (float*)d_out;

    char* ws = (char*)d_ws;
    _Float16* Af16 = (_Float16*)(ws);                 // 9088*512*2  = 9,306,112
    _Float16* Wt   = (_Float16*)(ws + 9306112);       // 3*512*512*2 = 1,572,864
    float* ecv = (float*)(ws + 10878976);             // 896*512*4   = 1,835,008
    float* ecg = (float*)(ws + 12713984);             // 4096*512*4  = 8,388,608
    float* ecs = (float*)(ws + 21102592);             // 4096*512*4  = 8,388,608

    void* args[] = {(void*)&V, (void*)&h_t, (void*)&s_t, (void*)&Wv, (void*)&Wg,
                    (void*)&Ws, (void*)&bv, (void*)&bg, (void*)&bs, (void*)&Wh,
                    (void*)&bh, (void*)&Af16, (void*)&Wt, (void*)&ecv, (void*)&ecg,
                    (void*)&ecs, (void*)&out};
    hipError_t err = hipLaunchCooperativeKernel((void*)fused_all, dim3(512), dim3(256),
                                                args, 16384, stream);
    if (err != hipSuccess) {
        // known-good 3-kernel path (identical math)
        conv_all<<<3040, 256, 0, stream>>>(V, h_t, s_t, Wv, Wg, Ws, Af16, Wt);
        gemm_f16<<<1136, 256, 0, stream>>>(Af16, Wt, bv, bg, bs, ecv, ecg, ecs);
        z_kernel<<<1024, 256, 0, stream>>>(ecv, ecg, ecs, V, s_t, Wh, bh, out);
    }
}

// Round 8
// 140.331 us; speedup vs baseline: 2.0297x; 2.0297x over previous
//
#include <hip/hip_runtime.h>
#include <hip/hip_fp16.h>
#include <cstdint>
#include <cstddef>

// Problem constants
#define B_ 16
#define K_ 49
#define T_ 256
#define H_ 512
#define D_ 512

// tanh(x) = 1 - 2*rcp(1 + 2^(x*2*log2e)); TANH_SCALE folded into Wv/Wg/Ws(+biases),
// gemm epilogue stores 2^(scaled dot) so z_kernel's inner loop is pure fma/rcp.
#define TANH_SCALE 2.8853900817779268f
#define LOG2E 1.4426950408889634f

typedef _Float16 half8 __attribute__((ext_vector_type(8)));
typedef float floatx4 __attribute__((ext_vector_type(4)));

// A matrix (fp16) rows: [0,784)=V, [784,896)=pad0, [896,4992)=h_t, [4992,9088)=s_t
#define OFF_V 0
#define OFF_H 896
#define OFF_S 4992

__device__ __forceinline__ void async16(const _Float16* g, const _Float16* l) {
    __builtin_amdgcn_global_load_lds(
        (const __attribute__((address_space(1))) unsigned int*)g,
        (__attribute__((address_space(3))) unsigned int*)l, 16, 0, 0);
}

__device__ __forceinline__ float wave_sum(float v) {
#pragma unroll
    for (int o = 32; o > 0; o >>= 1) v += __shfl_xor(v, o);
    return v;
}
__device__ __forceinline__ float wave_max(float v) {
#pragma unroll
    for (int o = 32; o > 0; o >>= 1) v = fmaxf(v, __shfl_xor(v, o));
    return v;
}

// ---------------- merged conversion kernel (R5) ----------------
__global__ __launch_bounds__(256) void conv_all(const float* __restrict__ V,
                                                const float* __restrict__ h_t,
                                                const float* __restrict__ s_t,
                                                const float* __restrict__ Wv,
                                                const float* __restrict__ Wg,
                                                const float* __restrict__ Ws,
                                                _Float16* __restrict__ Af16,
                                                _Float16* __restrict__ Wt) {
    __shared__ float tile[32][33];
    int tid = threadIdx.x;
    if (blockIdx.x < 2272) {
        int idx = (blockIdx.x * 256 + tid) * 8;
        int row = idx >> 9;
        int col = idx & 511;
        const float* src;
        if (row < 784)        src = V   + (size_t)row * 512 + col;
        else if (row < 896)   src = nullptr;
        else if (row < 4992)  src = h_t + (size_t)(row - 896) * 512 + col;
        else                  src = s_t + (size_t)(row - 4992) * 512 + col;
        half8 h;
        if (src) {
            float4 f0 = *(const float4*)(src);
            float4 f1 = *(const float4*)(src + 4);
            h[0] = (_Float16)f0.x; h[1] = (_Float16)f0.y;
            h[2] = (_Float16)f0.z; h[3] = (_Float16)f0.w;
            h[4] = (_Float16)f1.x; h[5] = (_Float16)f1.y;
            h[6] = (_Float16)f1.z; h[7] = (_Float16)f1.w;
        } else {
            h = (half8)((_Float16)0.0f);
        }
        *(half8*)(Af16 + idx) = h;
    } else {
        int bid = blockIdx.x - 2272;
        int p = bid >> 8;
        int rem = bid & 255;
        int bx = rem & 15, by = rem >> 4;
        const float* W = (p == 0) ? Wv : (p == 1) ? Wg : Ws;
        _Float16* outp = Wt + (size_t)p * 512 * 512;
        int tx = tid & 31, ty = tid >> 5;
        int c = bx * 32 + tx;
        int rbase = by * 32;
#pragma unroll
        for (int i = 0; i < 4; i++)
            tile[ty + i * 8][tx] = W[(size_t)(rbase + ty + i * 8) * 512 + c];
        __syncthreads();
        int k = rbase + tx;
#pragma unroll
        for (int i = 0; i < 4; i++) {
            int n = bx * 32 + ty + i * 8;
            outp[(size_t)n * 512 + k] = (_Float16)(tile[tx][ty + i * 8] * TANH_SCALE);
        }
    }
}

// ---------------- 3-problem fp16 MFMA GEMM, 64x64 tiles, 1136 blocks (R5) ----------------
// C = 2^(A @ W^T + bias)
__global__ __launch_bounds__(256) void gemm_f16(
    const _Float16* __restrict__ Af16, const _Float16* __restrict__ Wt,
    const float* __restrict__ bv, const float* __restrict__ bg2,
    const float* __restrict__ bs, float* __restrict__ cv,
    float* __restrict__ cg2, float* __restrict__ cs) {
    __shared__ __align__(16) _Float16 As[64 * 64];
    __shared__ __align__(16) _Float16 Bs[64 * 64];

    int id = blockIdx.x;
    int rowbase; const _Float16* Bt; const float* bias; float* C;
    if (id < 112)       { rowbase = OFF_V;            Bt = Wt;          bias = bv;  C = cv; }
    else if (id < 624)  { id -= 112; rowbase = OFF_H; Bt = Wt + 262144; bias = bg2; C = cg2; }
    else                { id -= 624; rowbase = OFF_S; Bt = Wt + 524288; bias = bs;  C = cs; }
    int tm = id >> 3, tn = id & 7;

    int tid = threadIdx.x;
    int wave = tid >> 6, lane = tid & 63;

    const _Float16* gA[2]; const _Float16* gB[2]; int ldsA[2];
#pragma unroll
    for (int i = 0; i < 2; i++) {
        int p = i * 256 + tid;
        int ks = p >> 8, x = (p >> 6) & 3, q = (p >> 4) & 3, f = p & 15;
        gA[i] = Af16 + (size_t)(rowbase + tm * 64 + x * 16 + f) * 512 + ks * 32 + q * 8;
        gB[i] = Bt   + (size_t)(tn * 64 + x * 16 + f) * 512 + ks * 32 + q * 8;
        ldsA[i] = p * 8;
    }

    floatx4 acc[4];
#pragma unroll
    for (int x = 0; x < 4; x++) acc[x] = (floatx4)0.0f;

    for (int kk = 0; kk < 8; kk++) {
        if (kk) __syncthreads();
#pragma unroll
        for (int i = 0; i < 2; i++) async16(gA[i] + kk * 64, As + ldsA[i]);
#pragma unroll
        for (int i = 0; i < 2; i++) async16(gB[i] + kk * 64, Bs + ldsA[i]);
        __syncthreads();

#pragma unroll
        for (int ks = 0; ks < 2; ks++) {
            half8 a[4];
#pragma unroll
            for (int x = 0; x < 4; x++)
                a[x] = *(const half8*)&As[(ks * 256 + x * 64 + lane) * 8];
            half8 b = *(const half8*)&Bs[(ks * 256 + wave * 64 + lane) * 8];
#pragma unroll
            for (int x = 0; x < 4; x++)
                acc[x] = __builtin_amdgcn_mfma_f32_16x16x32_f16(a[x], b, acc[x], 0, 0, 0);
        }
    }

    int dn = lane & 15, dq = lane >> 4;
    int colg = tn * 64 + wave * 16 + dn;
    float bc = bias[colg] * TANH_SCALE;
#pragma unroll
    for (int x = 0; x < 4; x++) {
        int rowg = tm * 64 + x * 16 + dq * 4;
#pragma unroll
        for (int r = 0; r < 4; r++)
            C[(size_t)(rowg + r) * 512 + colg] = __builtin_amdgcn_exp2f(acc[x][r] + bc);
    }
}

// ---------------- z / softmax / c_t / gate: TB=2, 2048 blocks (8 blocks/CU) ----------------
__global__ __launch_bounds__(256) void z_kernel(
    const float* __restrict__ ecv, const float* __restrict__ ecg,
    const float* __restrict__ ecs, const float* __restrict__ V,
    const float* __restrict__ s_t, const float* __restrict__ Wh,
    const float* __restrict__ bh, float* __restrict__ out) {
    int bx = blockIdx.x;           // 2048 blocks: b*128 + tpair
    int b  = bx >> 7;
    int t0 = (bx & 127) << 1;
    int bt0 = b * 256 + t0;
    int tid = threadIdx.x;
    int wave = tid >> 6, lane = tid & 63;

    __shared__ float zl[2][64];
    __shared__ float2 al2[52];
    __shared__ float bl[2];

    // register-resident Wh and egv = 2^cg (d = j*64 + lane fixed per lane)
    float whv[8], egv[2][8];
#pragma unroll
    for (int j = 0; j < 8; j++) whv[j] = Wh[j * 64 + lane];
#pragma unroll
    for (int tt = 0; tt < 2; tt++) {
        const float* cgp = ecg + (size_t)(bt0 + tt) * 512;
#pragma unroll
        for (int j = 0; j < 8; j++) egv[tt][j] = cgp[j * 64 + lane];
    }
    float s8 = 0.0f;
#pragma unroll
    for (int j = 0; j < 8; j++) s8 += whv[j];
    float zbase = wave_sum(s8) + bh[0];   // sum(Wh)+bh: tanh = 1-2r folded

    // 49 content tasks round-robin over 4 waves, software-prefetched
    float rv[8], rn[8];
    {
        const float* rp = ecv + (size_t)(b * 49 + wave) * 512;
#pragma unroll
        for (int j = 0; j < 8; j++) rv[j] = rp[j * 64 + lane];
    }
    for (int task = wave; task < 49; task += 4) {
        int nt = task + 4;
        if (nt < 49) {
            const float* rp = ecv + (size_t)(b * 49 + nt) * 512;
#pragma unroll
            for (int j = 0; j < 8; j++) rn[j] = rp[j * 64 + lane];
        }
        float a0 = 0.0f, a1 = 0.0f;
#pragma unroll
        for (int j = 0; j < 8; j++) {
            float e0 = fmaf(rv[j], egv[0][j], 1.0f);   // 1 + 2^(cv+cg)
            float e1 = fmaf(rv[j], egv[1][j], 1.0f);
            a0 = fmaf(whv[j], __builtin_amdgcn_rcpf(e0), a0);
            a1 = fmaf(whv[j], __builtin_amdgcn_rcpf(e1), a1);
        }
        // xsum2: group g = lane>>5 ends holding total of acc_g over 64 lanes
        bool hi = (lane & 32) != 0;
        float t = hi ? a0 : a1;
        t = __shfl_xor(t, 32);
        float s = (hi ? a1 : a0) + t;
#pragma unroll
        for (int o = 16; o > 0; o >>= 1) s += __shfl_xor(s, o);
        if ((lane & 31) == 0) zl[lane >> 5][task] = zbase - 2.0f * s;
#pragma unroll
        for (int j = 0; j < 8; j++) rv[j] = rn[j];
    }
    // ext tasks: wave tt handles row bt0+tt (tt = 0,1), reusing egv[tt]
#pragma unroll
    for (int tt = 0; tt < 2; tt++) {
        if (wave == tt) {
            const float* rp = ecs + (size_t)(bt0 + tt) * 512;
            float acc = 0.0f;
#pragma unroll
            for (int j = 0; j < 8; j++) {
                float e = fmaf(rp[j * 64 + lane], egv[tt][j], 1.0f);
                acc = fmaf(whv[j], __builtin_amdgcn_rcpf(e), acc);
            }
            float s = wave_sum(acc);
            if (lane == 0) zl[tt][49] = zbase - 2.0f * s;
        }
    }
    __syncthreads();

    // 2 softmaxes in parallel: waves 0,1
    if (wave < 2) {
        int w = wave;
        float z = (lane < 49) ? zl[w][lane] : -3.0e38f;
        float m = wave_max(z);
        float e = (lane < 49) ? __builtin_amdgcn_exp2f((z - m) * LOG2E) : 0.0f;
        float s = wave_sum(e);
        float zext = zl[w][49];
        float m2 = fmaxf(m, zext);
        float sc   = __builtin_amdgcn_exp2f((m - m2) * LOG2E);
        float eext = __builtin_amdgcn_exp2f((zext - m2) * LOG2E);
        float s2 = s * sc + eext;
        float beta = eext / s2;
        if (lane < 49) {
            float a = e / s;
            ((float*)(al2 + lane))[w] = a;
            out[(size_t)B_ * T_ * H_ + (size_t)(bt0 + w) * 49 + lane] = a;   // alpha_t
        }
        if (lane == 0) {
            bl[w] = beta;
            out[(size_t)B_ * T_ * H_ + (size_t)B_ * T_ * K_ + (bt0 + w)] = beta;  // beta_t
        }
    }
    __syncthreads();

    // c_t + gate: float2 per lane, V read once per block
    const float* Vb = V + (size_t)b * 49 * 512;
    float2 acc0 = make_float2(0.0f, 0.0f), acc1 = make_float2(0.0f, 0.0f);
#pragma unroll 7
    for (int k = 0; k < 49; k++) {
        float2 a2 = al2[k];
        float2 v = *(const float2*)(Vb + (size_t)k * 512 + tid * 2);
        acc0.x = fmaf(a2.x, v.x, acc0.x);  acc0.y = fmaf(a2.x, v.y, acc0.y);
        acc1.x = fmaf(a2.y, v.x, acc1.x);  acc1.y = fmaf(a2.y, v.y, acc1.y);
    }
#pragma unroll
    for (int tt = 0; tt < 2; tt++) {
        float beta = bl[tt];
        float2 a = (tt == 0) ? acc0 : acc1;
        float2 sp = *(const float2*)(s_t + (size_t)(bt0 + tt) * 512 + tid * 2);
        float2 o;
        o.x = beta * sp.x + (1.0f - beta) * a.x;
        o.y = beta * sp.y + (1.0f - beta) * a.y;
        *(float2*)(out + (size_t)(bt0 + tt) * 512 + tid * 2) = o;
    }
}

// ---------------- launch ----------------
extern "C" void kernel_launch(void* const* d_in, const int* in_sizes, int n_in,
                              void* d_out, int out_size, void* d_ws, size_t ws_size,
                              hipStream_t stream) {
    const float* V   = (const float*)d_in[0];
    const float* h_t = (const float*)d_in[1];
    const float* s_t = (const float*)d_in[2];
    const float* Wv  = (const float*)d_in[3];
    const float* bv  = (const float*)d_in[4];
    const float* Wg  = (const float*)d_in[5];
    const float* bg  = (const float*)d_in[6];
    const float* Ws  = (const float*)d_in[7];
    const float* bs  = (const float*)d_in[8];
    const float* Wh  = (const float*)d_in[9];
    const float* bh  = (const float*)d_in[10];
    float* out = (float*)d_out;

    char* ws = (char*)d_ws;
    _Float16* Af16 = (_Float16*)(ws);                 // 9088*512*2  = 9,306,112
    _Float16* Wt   = (_Float16*)(ws + 9306112);       // 3*512*512*2 = 1,572,864
    float* ecv = (float*)(ws + 10878976);             // 896*512*4   = 1,835,008
    float* ecg = (float*)(ws + 12713984);             // 4096*512*4  = 8,388,608
    float* ecs = (float*)(ws + 21102592);             // 4096*512*4  = 8,388,608

    conv_all<<<3040, 256, 0, stream>>>(V, h_t, s_t, Wv, Wg, Ws, Af16, Wt);
    gemm_f16<<<1136, 256, 0, stream>>>(Af16, Wt, bv, bg, bs, ecv, ecg, ecs);
    z_kernel<<<2048, 256, 0, stream>>>(ecv, ecg, ecs, V, s_t, Wh, bh, out);
}

// Round 9
// 135.346 us; speedup vs baseline: 2.1045x; 1.0368x over previous
//
#include <hip/hip_runtime.h>
#include <hip/hip_fp16.h>
#include <cstdint>
#include <cstddef>

// Problem constants
#define B_ 16
#define K_ 49
#define T_ 256
#define H_ 512
#define D_ 512

// tanh(x) = 1 - 2*rcp(1 + 2^(x*2*log2e)); TANH_SCALE folded into Wv/Wg/Ws(+biases),
// gemm epilogue stores 2^(scaled dot) so z_kernel's inner loop is pure fma/rcp.
#define TANH_SCALE 2.8853900817779268f
#define LOG2E 1.4426950408889634f

typedef _Float16 half8 __attribute__((ext_vector_type(8)));
typedef float floatx4 __attribute__((ext_vector_type(4)));

// A matrix (fp16) rows: [0,784)=V, [784,896)=pad0, [896,4992)=h_t, [4992,9088)=s_t
#define OFF_V 0
#define OFF_H 896
#define OFF_S 4992

__device__ __forceinline__ void async16(const _Float16* g, const _Float16* l) {
    __builtin_amdgcn_global_load_lds(
        (const __attribute__((address_space(1))) unsigned int*)g,
        (__attribute__((address_space(3))) unsigned int*)l, 16, 0, 0);
}

__device__ __forceinline__ float wave_sum(float v) {
#pragma unroll
    for (int o = 32; o > 0; o >>= 1) v += __shfl_xor(v, o);
    return v;
}
__device__ __forceinline__ float wave_max(float v) {
#pragma unroll
    for (int o = 32; o > 0; o >>= 1) v = fmaxf(v, __shfl_xor(v, o));
    return v;
}
// Sum 4 independent values across 64 lanes (group g=lane>>4 holds acc_g's total).
__device__ __forceinline__ float xsum4(float a0, float a1, float a2, float a3, int lane) {
    bool hi = (lane & 32) != 0;
    float t0 = hi ? a0 : a2;
    float t1 = hi ? a1 : a3;
    t0 = __shfl_xor(t0, 32);
    t1 = __shfl_xor(t1, 32);
    if (hi) { a0 = t0; a1 = t1; } else { a2 = t0; a3 = t1; }
    bool h2 = (lane & 16) != 0;
    float u0 = h2 ? a0 : a1;
    float u1 = h2 ? a2 : a3;
    u0 = __shfl_xor(u0, 16);
    u1 = __shfl_xor(u1, 16);
    if (h2) { a0 = u0; a2 = u1; } else { a1 = u0; a3 = u1; }
    float s = (a0 + a1) + (a2 + a3);
#pragma unroll
    for (int o = 8; o > 0; o >>= 1) s += __shfl_xor(s, o);
    return s;
}

// ---------------- merged conversion kernel (R5) ----------------
__global__ __launch_bounds__(256) void conv_all(const float* __restrict__ V,
                                                const float* __restrict__ h_t,
                                                const float* __restrict__ s_t,
                                                const float* __restrict__ Wv,
                                                const float* __restrict__ Wg,
                                                const float* __restrict__ Ws,
                                                _Float16* __restrict__ Af16,
                                                _Float16* __restrict__ Wt) {
    __shared__ float tile[32][33];
    int tid = threadIdx.x;
    if (blockIdx.x < 2272) {
        int idx = (blockIdx.x * 256 + tid) * 8;
        int row = idx >> 9;
        int col = idx & 511;
        const float* src;
        if (row < 784)        src = V   + (size_t)row * 512 + col;
        else if (row < 896)   src = nullptr;
        else if (row < 4992)  src = h_t + (size_t)(row - 896) * 512 + col;
        else                  src = s_t + (size_t)(row - 4992) * 512 + col;
        half8 h;
        if (src) {
            float4 f0 = *(const float4*)(src);
            float4 f1 = *(const float4*)(src + 4);
            h[0] = (_Float16)f0.x; h[1] = (_Float16)f0.y;
            h[2] = (_Float16)f0.z; h[3] = (_Float16)f0.w;
            h[4] = (_Float16)f1.x; h[5] = (_Float16)f1.y;
            h[6] = (_Float16)f1.z; h[7] = (_Float16)f1.w;
        } else {
            h = (half8)((_Float16)0.0f);
        }
        *(half8*)(Af16 + idx) = h;
    } else {
        int bid = blockIdx.x - 2272;
        int p = bid >> 8;
        int rem = bid & 255;
        int bx = rem & 15, by = rem >> 4;
        const float* W = (p == 0) ? Wv : (p == 1) ? Wg : Ws;
        _Float16* outp = Wt + (size_t)p * 512 * 512;
        int tx = tid & 31, ty = tid >> 5;
        int c = bx * 32 + tx;
        int rbase = by * 32;
#pragma unroll
        for (int i = 0; i < 4; i++)
            tile[ty + i * 8][tx] = W[(size_t)(rbase + ty + i * 8) * 512 + c];
        __syncthreads();
        int k = rbase + tx;
#pragma unroll
        for (int i = 0; i < 4; i++) {
            int n = bx * 32 + ty + i * 8;
            outp[(size_t)n * 512 + k] = (_Float16)(tile[tx][ty + i * 8] * TANH_SCALE);
        }
    }
}

// ---------------- 3-problem fp16 MFMA GEMM, 64x64 tiles, 1136 blocks (R5) ----------------
// C = 2^(A @ W^T + bias)
__global__ __launch_bounds__(256) void gemm_f16(
    const _Float16* __restrict__ Af16, const _Float16* __restrict__ Wt,
    const float* __restrict__ bv, const float* __restrict__ bg2,
    const float* __restrict__ bs, float* __restrict__ cv,
    float* __restrict__ cg2, float* __restrict__ cs) {
    __shared__ __align__(16) _Float16 As[64 * 64];
    __shared__ __align__(16) _Float16 Bs[64 * 64];

    int id = blockIdx.x;
    int rowbase; const _Float16* Bt; const float* bias; float* C;
    if (id < 112)       { rowbase = OFF_V;            Bt = Wt;          bias = bv;  C = cv; }
    else if (id < 624)  { id -= 112; rowbase = OFF_H; Bt = Wt + 262144; bias = bg2; C = cg2; }
    else                { id -= 624; rowbase = OFF_S; Bt = Wt + 524288; bias = bs;  C = cs; }
    int tm = id >> 3, tn = id & 7;

    int tid = threadIdx.x;
    int wave = tid >> 6, lane = tid & 63;

    const _Float16* gA[2]; const _Float16* gB[2]; int ldsA[2];
#pragma unroll
    for (int i = 0; i < 2; i++) {
        int p = i * 256 + tid;
        int ks = p >> 8, x = (p >> 6) & 3, q = (p >> 4) & 3, f = p & 15;
        gA[i] = Af16 + (size_t)(rowbase + tm * 64 + x * 16 + f) * 512 + ks * 32 + q * 8;
        gB[i] = Bt   + (size_t)(tn * 64 + x * 16 + f) * 512 + ks * 32 + q * 8;
        ldsA[i] = p * 8;
    }

    floatx4 acc[4];
#pragma unroll
    for (int x = 0; x < 4; x++) acc[x] = (floatx4)0.0f;

    for (int kk = 0; kk < 8; kk++) {
        if (kk) __syncthreads();
#pragma unroll
        for (int i = 0; i < 2; i++) async16(gA[i] + kk * 64, As + ldsA[i]);
#pragma unroll
        for (int i = 0; i < 2; i++) async16(gB[i] + kk * 64, Bs + ldsA[i]);
        __syncthreads();

#pragma unroll
        for (int ks = 0; ks < 2; ks++) {
            half8 a[4];
#pragma unroll
            for (int x = 0; x < 4; x++)
                a[x] = *(const half8*)&As[(ks * 256 + x * 64 + lane) * 8];
            half8 b = *(const half8*)&Bs[(ks * 256 + wave * 64 + lane) * 8];
#pragma unroll
            for (int x = 0; x < 4; x++)
                acc[x] = __builtin_amdgcn_mfma_f32_16x16x32_f16(a[x], b, acc[x], 0, 0, 0);
        }
    }

    int dn = lane & 15, dq = lane >> 4;
    int colg = tn * 64 + wave * 16 + dn;
    float bc = bias[colg] * TANH_SCALE;
#pragma unroll
    for (int x = 0; x < 4; x++) {
        int rowg = tm * 64 + x * 16 + dq * 4;
#pragma unroll
        for (int r = 0; r < 4; r++)
            C[(size_t)(rowg + r) * 512 + colg] = __builtin_amdgcn_exp2f(acc[x][r] + bc);
    }
}

// ---------------- z / softmax / c_t / gate: TB=4, 1024 blocks (R5) ----------------
// XCD swizzle: b = bx & 15 => all 64 blocks of batch b are congruent mod 8
// => same XCD => V_b/ecv_b stay L2-resident instead of being fetched by 8 XCDs.
#define TB 4
__global__ __launch_bounds__(256) void z_kernel(
    const float* __restrict__ ecv, const float* __restrict__ ecg,
    const float* __restrict__ ecs, const float* __restrict__ V,
    const float* __restrict__ s_t, const float* __restrict__ Wh,
    const float* __restrict__ bh, float* __restrict__ out) {
    int bx = blockIdx.x;           // 1024 blocks
    int b  = bx & 15;              // XCD-local batch grouping
    int t0 = (bx >> 4) << 2;
    int bt0 = b * 256 + t0;
    int tid = threadIdx.x;
    int wave = tid >> 6, lane = tid & 63;

    __shared__ float zl[TB][64];
    __shared__ float4 al4[52];
    __shared__ float bl[TB];

    // register-resident Wh and egv = 2^cg (d = j*64 + lane fixed per lane)
    float whv[8], egv[TB][8];
#pragma unroll
    for (int j = 0; j < 8; j++) whv[j] = Wh[j * 64 + lane];
#pragma unroll
    for (int tt = 0; tt < TB; tt++) {
        const float* cgp = ecg + (size_t)(bt0 + tt) * 512;
#pragma unroll
        for (int j = 0; j < 8; j++) egv[tt][j] = cgp[j * 64 + lane];
    }
    float s8 = 0.0f;
#pragma unroll
    for (int j = 0; j < 8; j++) s8 += whv[j];
    float zbase = wave_sum(s8) + bh[0];   // sum(Wh)+bh: tanh = 1-2r folded

    // 49 content tasks round-robin over 4 waves, software-prefetched
    float rv[8], rn[8];
    {
        const float* rp = ecv + (size_t)(b * 49 + wave) * 512;
#pragma unroll
        for (int j = 0; j < 8; j++) rv[j] = rp[j * 64 + lane];
    }
    for (int task = wave; task < 49; task += 4) {
        int nt = task + 4;
        if (nt < 49) {
            const float* rp = ecv + (size_t)(b * 49 + nt) * 512;
#pragma unroll
            for (int j = 0; j < 8; j++) rn[j] = rp[j * 64 + lane];
        }
        float acc[TB] = {0.0f, 0.0f, 0.0f, 0.0f};
#pragma unroll
        for (int tt = 0; tt < TB; tt++) {
#pragma unroll
            for (int j = 0; j < 8; j++) {
                float t = fmaf(rv[j], egv[tt][j], 1.0f);   // 1 + 2^(cv+cg)
                float r = __builtin_amdgcn_rcpf(t);
                acc[tt] = fmaf(whv[j], r, acc[tt]);
            }
        }
        float z = xsum4(acc[0], acc[1], acc[2], acc[3], lane);
        if ((lane & 15) == 0) zl[lane >> 4][task] = zbase - 2.0f * z;
#pragma unroll
        for (int j = 0; j < 8; j++) rv[j] = rn[j];
    }
    // ext task: wave tt handles t0+tt (reuses egv[tt])
#pragma unroll
    for (int tt = 0; tt < TB; tt++) {
        if (wave == tt) {
            const float* rp = ecs + (size_t)(bt0 + tt) * 512;
            float acc = 0.0f;
#pragma unroll
            for (int j = 0; j < 8; j++) {
                float t = fmaf(rp[j * 64 + lane], egv[tt][j], 1.0f);
                float r = __builtin_amdgcn_rcpf(t);
                acc = fmaf(whv[j], r, acc);
            }
            float s = wave_sum(acc);
            if (lane == 0) zl[tt][49] = zbase - 2.0f * s;
        }
    }
    __syncthreads();

    // 4 softmaxes in parallel: wave w handles tt=w
    {
        int w = wave;
        float z = (lane < 49) ? zl[w][lane] : -3.0e38f;
        float m = wave_max(z);
        float e = (lane < 49) ? __builtin_amdgcn_exp2f((z - m) * LOG2E) : 0.0f;
        float s = wave_sum(e);
        float zext = zl[w][49];
        float m2 = fmaxf(m, zext);
        float sc   = __builtin_amdgcn_exp2f((m - m2) * LOG2E);
        float eext = __builtin_amdgcn_exp2f((zext - m2) * LOG2E);
        float s2 = s * sc + eext;
        float beta = eext / s2;
        if (lane < 49) {
            float a = e / s;
            ((float*)&al4[lane])[w] = a;
            out[(size_t)B_ * T_ * H_ + (size_t)(bt0 + w) * 49 + lane] = a;   // alpha_t
        }
        if (lane == 0) {
            bl[w] = beta;
            out[(size_t)B_ * T_ * H_ + (size_t)B_ * T_ * K_ + (bt0 + w)] = beta;  // beta_t
        }
    }
    __syncthreads();

    // c_t + gate: float2 per lane, V read once per block
    const float* Vb = V + (size_t)b * 49 * 512;
    float2 accA[TB];
#pragma unroll
    for (int tt = 0; tt < TB; tt++) accA[tt] = make_float2(0.0f, 0.0f);
#pragma unroll 7
    for (int k = 0; k < 49; k++) {
        float4 a4 = al4[k];
        float2 v = *(const float2*)(Vb + (size_t)k * 512 + tid * 2);
        accA[0].x = fmaf(a4.x, v.x, accA[0].x);  accA[0].y = fmaf(a4.x, v.y, accA[0].y);
        accA[1].x = fmaf(a4.y, v.x, accA[1].x);  accA[1].y = fmaf(a4.y, v.y, accA[1].y);
        accA[2].x = fmaf(a4.z, v.x, accA[2].x);  accA[2].y = fmaf(a4.z, v.y, accA[2].y);
        accA[3].x = fmaf(a4.w, v.x, accA[3].x);  accA[3].y = fmaf(a4.w, v.y, accA[3].y);
    }
#pragma unroll
    for (int tt = 0; tt < TB; tt++) {
        float beta = bl[tt];
        float2 sp = *(const float2*)(s_t + (size_t)(bt0 + tt) * 512 + tid * 2);
        float2 o;
        o.x = beta * sp.x + (1.0f - beta) * accA[tt].x;
        o.y = beta * sp.y + (1.0f - beta) * accA[tt].y;
        *(float2*)(out + (size_t)(bt0 + tt) * 512 + tid * 2) = o;
    }
}

// ---------------- launch ----------------
extern "C" void kernel_launch(void* const* d_in, const int* in_sizes, int n_in,
                              void* d_out, int out_size, void* d_ws, size_t ws_size,
                              hipStream_t stream) {
    const float* V   = (const float*)d_in[0];
    const float* h_t = (const float*)d_in[1];
    const float* s_t = (const float*)d_in[2];
    const float* Wv  = (const float*)d_in[3];
    const float* bv  = (const float*)d_in[4];
    const float* Wg  = (const float*)d_in[5];
    const float* bg  = (const float*)d_in[6];
    const float* Ws  = (const float*)d_in[7];
    const float* bs  = (const float*)d_in[8];
    const float* Wh  = (const float*)d_in[9];
    const float* bh  = (const float*)d_in[10];
    float* out = (float*)d_out;

    char* ws = (char*)d_ws;
    _Float16* Af16 = (_Float16*)(ws);                 // 9088*512*2  = 9,306,112
    _Float16* Wt   = (_Float16*)(ws + 9306112);       // 3*512*512*2 = 1,572,864
    float* ecv = (float*)(ws + 10878976);             // 896*512*4   = 1,835,008
    float* ecg = (float*)(ws + 12713984);             // 4096*512*4  = 8,388,608
    float* ecs = (float*)(ws + 21102592);             // 4096*512*4  = 8,388,608

    conv_all<<<3040, 256, 0, stream>>>(V, h_t, s_t, Wv, Wg, Ws, Af16, Wt);
    gemm_f16<<<1136, 256, 0, stream>>>(Af16, Wt, bv, bg, bs, ecv, ecg, ecs);
    z_kernel<<<1024, 256, 0, stream>>>(ecv, ecg, ecs, V, s_t, Wh, bh, out);
}